// Round 12
// baseline (6133.090 us; speedup 1.0000x reference)
//
#include <hip/hip_runtime.h>

typedef unsigned short u16;
typedef unsigned int u32;
typedef __attribute__((ext_vector_type(8))) short s16x8;
typedef __attribute__((ext_vector_type(8))) u16 u16x8;
typedef __attribute__((ext_vector_type(4))) u16 u16x4;
typedef __attribute__((ext_vector_type(4))) u32 u32x4;
typedef __attribute__((ext_vector_type(4))) float f32x4;
typedef __attribute__((ext_vector_type(2))) float f32x2;

#define L2E 1.4426950408889634f

__device__ __forceinline__ u16 f2bf(float f) {
  unsigned u = __builtin_bit_cast(unsigned, f);
  u = (u + 0x7fffu + ((u >> 16) & 1u)) >> 16;
  return (u16)u;
}
__device__ __forceinline__ float bf2f(u16 s) {
  unsigned u = ((unsigned)s) << 16;
  return __builtin_bit_cast(float, u);
}
__device__ __forceinline__ float blo(u32 d) { return __builtin_bit_cast(float, d << 16); }
__device__ __forceinline__ float bhi(u32 d) { return __builtin_bit_cast(float, d & 0xFFFF0000u); }
__device__ __forceinline__ float sigmoidf_(float x) { return 1.f / (1.f + __expf(-x)); }
__device__ __forceinline__ float softplusf_(float x) { return (x > 20.f) ? x : logf(1.f + __expf(x)); }

// packed f32 (VOP3P) helpers; _s* variants take the block-uniform operand in an SGPR pair
__device__ __forceinline__ f32x2 pk_fma_vvv(f32x2 a, f32x2 b, f32x2 c) {
  f32x2 d;
  asm("v_pk_fma_f32 %0, %1, %2, %3" : "=v"(d) : "v"(a), "v"(b), "v"(c));
  return d;
}
__device__ __forceinline__ f32x2 pk_fma_svv(f32x2 a, f32x2 b, f32x2 c) {
  f32x2 d;
  asm("v_pk_fma_f32 %0, %1, %2, %3" : "=v"(d) : "s"(a), "v"(b), "v"(c));
  return d;
}

// wave64 sum via DPP; full total lands in lane 63, broadcast via readlane.
template <int CTRL, int RMASK>
__device__ __forceinline__ float dpp_add(float v) {
  int x = __builtin_amdgcn_update_dpp(0, __builtin_bit_cast(int, v), CTRL, RMASK, 0xf, true);
  return v + __builtin_bit_cast(float, x);
}
__device__ __forceinline__ float wred_sum_dpp(float v) {
  v = dpp_add<0x111, 0xf>(v);
  v = dpp_add<0x112, 0xf>(v);
  v = dpp_add<0x114, 0xf>(v);
  v = dpp_add<0x118, 0xf>(v);
  v = dpp_add<0x142, 0xa>(v);
  v = dpp_add<0x143, 0xc>(v);
  return __builtin_bit_cast(float, __builtin_amdgcn_readlane(__builtin_bit_cast(int, v), 63));
}

__device__ __forceinline__ float wred_sum(float v) {
  #pragma unroll
  for (int d = 1; d < 64; d <<= 1) v += __shfl_xor(v, d);
  return v;
}
__device__ __forceinline__ float wred_max(float v) {
  #pragma unroll
  for (int d = 1; d < 64; d <<= 1) v = fmaxf(v, __shfl_xor(v, d));
  return v;
}

// ---------------- cast kernels ----------------
__global__ void castx_k(const float* __restrict__ in, u16* __restrict__ out, int n4) {
  int i = blockIdx.x * 256 + threadIdx.x;
  if (i < n4) {
    f32x4 v = *(const f32x4*)(in + (long)i * 4);
    u16x4 o;
    o.x = f2bf(v.x); o.y = f2bf(v.y); o.z = f2bf(v.z); o.w = f2bf(v.w);
    *(u16x4*)(out + (long)i * 4) = o;
  }
}

// f32 (K,N) row-major -> bf16 (N,K) row-major, batched over z
__global__ void castT_k(const float* __restrict__ in, u16* __restrict__ out, int K, int N) {
  long base = (long)blockIdx.z * K * N;
  int idx = blockIdx.x * 256 + threadIdx.x;
  if (idx < K * N) {
    int n = idx / K, k = idx - n * K;
    out[base + idx] = f2bf(in[base + (long)k * N + n]);
  }
}

// extract transposed V: vT[(b,h)][d][s] = qkv[(b,s)][2H + h*64 + d]
__global__ void vtx_k(const u16* __restrict__ qkv, u16* __restrict__ vT) {
  int idx = blockIdx.x * 256 + threadIdx.x;
  int s = idx & 511;
  int d = (idx >> 9) & 63;
  int bh = idx >> 15;
  int b = bh >> 3, h = bh & 7;
  vT[idx] = qkv[((long)(b * 512 + s)) * 1536 + 1024 + h * 64 + d];
}

// ---------------- GEMM (bf16 MFMA, B passed as B^T = (N,K) row-major) ----------------
struct GemmP {
  const u16* A; const u16* B; const float* bias;
  float* outF; u16* outB;
  int M, N, K, lda, ldb, ldc;
  long sAb, sAh, sAz, sBb, sBh, sBz, sCb, sCh, sCz;
  int zdiv, z0;
  float alpha; int relu;
};

__global__ __launch_bounds__(256) void gemm_k(GemmP p) {
  __shared__ u16 sA[128 * 72];
  __shared__ u16 sB[128 * 72];
  int tid = threadIdx.x;
  int gp = p.z0 + blockIdx.z;
  int zb = gp / p.zdiv, zh = gp - zb * p.zdiv;
  const u16* Ab = p.A + zb * p.sAb + zh * p.sAh + (long)blockIdx.z * p.sAz + (long)blockIdx.x * 128 * p.lda;
  const u16* Bb = p.B + zb * p.sBb + zh * p.sBh + (long)blockIdx.z * p.sBz;
  long coff = zb * p.sCb + zh * p.sCh + (long)blockIdx.z * p.sCz;
  int bn = blockIdx.y * 128;
  int lane = tid & 63, wid = tid >> 6;
  int wr = wid >> 1, wc = wid & 1;

  f32x4 acc[4][4];
  f32x4 z4 = {0.f, 0.f, 0.f, 0.f};
  #pragma unroll
  for (int i = 0; i < 4; i++)
    #pragma unroll
    for (int j = 0; j < 4; j++) acc[i][j] = z4;

  int r = tid >> 1, c32 = (tid & 1) * 32;
  for (int k0 = 0; k0 < p.K; k0 += 64) {
    const u16* Ag = Ab + (long)r * p.lda + k0 + c32;
    u16x8* dA = (u16x8*)(sA + r * 72 + c32);
    #pragma unroll
    for (int i = 0; i < 4; i++) dA[i] = *(const u16x8*)(Ag + i * 8);
    int nrow = bn + r;
    u16x8* dB = (u16x8*)(sB + r * 72 + c32);
    if (nrow < p.N) {
      const u16* Bg = Bb + (long)nrow * p.ldb + k0 + c32;
      #pragma unroll
      for (int i = 0; i < 4; i++) dB[i] = *(const u16x8*)(Bg + i * 8);
    } else {
      u16x8 zz = (u16x8)0;
      #pragma unroll
      for (int i = 0; i < 4; i++) dB[i] = zz;
    }
    __syncthreads();
    #pragma unroll
    for (int ks = 0; ks < 2; ks++) {
      int ko = ks * 32 + (lane >> 4) * 8;
      s16x8 af[4], bf[4];
      #pragma unroll
      for (int m = 0; m < 4; m++) af[m] = *(const s16x8*)(sA + (wr * 64 + m * 16 + (lane & 15)) * 72 + ko);
      #pragma unroll
      for (int n = 0; n < 4; n++) bf[n] = *(const s16x8*)(sB + (wc * 64 + n * 16 + (lane & 15)) * 72 + ko);
      #pragma unroll
      for (int m = 0; m < 4; m++)
        #pragma unroll
        for (int n = 0; n < 4; n++)
          acc[m][n] = __builtin_amdgcn_mfma_f32_16x16x32_bf16(af[m], bf[n], acc[m][n], 0, 0, 0);
    }
    __syncthreads();
  }

  int row0 = blockIdx.x * 128 + wr * 64;
  int col0 = bn + wc * 64;
  #pragma unroll
  for (int n = 0; n < 4; n++) {
    int col = col0 + n * 16 + (lane & 15);
    if (col >= p.N) continue;
    float bv = p.bias ? p.bias[col] : 0.f;
    #pragma unroll
    for (int m = 0; m < 4; m++) {
      #pragma unroll
      for (int q = 0; q < 4; q++) {
        int row = row0 + m * 16 + (lane >> 4) * 4 + q;
        float v = acc[m][n][q] * p.alpha + bv;
        if (p.relu) v = fmaxf(v, 0.f);
        long ci = coff + (long)row * p.ldc + col;
        if (p.outF) p.outF[ci] = v;
        if (p.outB) p.outB[ci] = f2bf(v);
      }
    }
  }
}

// ---------------- fused residual + LayerNorm ----------------
__global__ __launch_bounds__(64) void ln_k(const float* __restrict__ a, const float* __restrict__ res,
                                           const float* __restrict__ g, const float* __restrict__ bb,
                                           float* __restrict__ outF, u16* __restrict__ outB) {
  int row = blockIdx.x, t = threadIdx.x;
  const float* ar = a + (long)row * 512;
  const float* rr = res + (long)row * 512;
  float x[8];
  float s1 = 0.f;
  #pragma unroll
  for (int i = 0; i < 8; i++) { x[i] = ar[i * 64 + t] + rr[i * 64 + t]; s1 += x[i]; }
  s1 = wred_sum(s1);
  float mean = s1 * (1.f / 512.f);
  float s2 = 0.f;
  #pragma unroll
  for (int i = 0; i < 8; i++) { float d = x[i] - mean; s2 += d * d; }
  s2 = wred_sum(s2);
  float inv = rsqrtf(s2 * (1.f / 512.f) + 1e-5f);
  #pragma unroll
  for (int i = 0; i < 8; i++) {
    int cc = i * 64 + t;
    float y = (x[i] - mean) * inv * g[cc] + bb[cc];
    outF[(long)row * 512 + cc] = y;
    outB[(long)row * 512 + cc] = f2bf(y);
  }
}

// ---------------- row softmax over bf16 (512 cols), in place ----------------
__global__ __launch_bounds__(64) void smaxb_k(u16* __restrict__ p) {
  long row = blockIdx.x;
  u16* pr = p + row * 512;
  int t = threadIdx.x;
  u16x8 v = *(const u16x8*)(pr + t * 8);
  float f[8];
  float mx = -1e30f;
  #pragma unroll
  for (int i = 0; i < 8; i++) { f[i] = bf2f(v[i]); mx = fmaxf(mx, f[i]); }
  mx = wred_max(mx);
  float se = 0.f;
  #pragma unroll
  for (int i = 0; i < 8; i++) { f[i] = __expf(f[i] - mx); se += f[i]; }
  se = wred_sum(se);
  float inv = __builtin_amdgcn_rcpf(se);
  #pragma unroll
  for (int i = 0; i < 8; i++) v[i] = f2bf(f[i] * inv);
  *(u16x8*)(pr + t * 8) = v;
}

// ---------------- DNC prep: fold norms/betas/log2e into keys, apply gates ----------------
// rec1 (stride 256 f32): [0:64]=wk*(wb*log2e/|wk|), [64:128]=-sigmoid(er),
//                        [128:192]=wv, [192]=gw
// rec2 (stride 512 f32): rk_h*(rb_h*log2e/|rk_h|)
__global__ __launch_bounds__(256) void prep_k(const float* __restrict__ iface,
                                              float* __restrict__ rec1,
                                              float* __restrict__ rec2) {
  int idx = blockIdx.x * 4 + (threadIdx.x >> 6);
  int lane = threadIdx.x & 63;
  const float* r = iface + (long)idx * 714;
  float* o1 = rec1 + ((long)idx << 8);
  float* o2 = rec2 + ((long)idx << 9);
  float wk = r[520 + lane];
  float s2k = wred_sum(wk * wk);
  float wb = softplusf_(r[584]);
  o1[lane] = wk * (wb * L2E * rsqrtf(s2k + 1e-8f));
  o1[64 + lane] = -sigmoidf_(r[585 + lane]);
  o1[128 + lane] = r[649 + lane];
  #pragma unroll
  for (int h = 0; h < 8; h++) {
    float rk = r[h * 64 + lane];
    float s2r = wred_sum(rk * rk);
    float rb = softplusf_(r[512 + h]);
    o2[h * 64 + lane] = rk * (rb * L2E * rsqrtf(s2r + 1e-8f));
  }
  if (!lane) o1[192] = sigmoidf_(r[713]);
}

// ---------------- DNC fused scan: producer (write pass) + consumers (read replay) ----
// grid (8 batches, 32 roles), 1024 threads, LDS 145KB -> exactly 1 block/CU,
// 256 blocks = 256 CUs, all co-resident. Role 0 runs the sequential write scan
// for its batch (publishing chunk progress with device-scope release every 16
// steps), then consumes chunk 0. Roles 1..31 acquire-wait once, then replay
// chunk `role`. Producers are linear block IDs 0..7 -> dispatched first.
#define P2_LDS 148480
__global__ __launch_bounds__(1024, 4) void fused_k(const float* __restrict__ rec1,
                                                   const float* __restrict__ rec2,
                                                   const float* __restrict__ M0,
                                                   float* __restrict__ ww_out,
                                                   u16* __restrict__ snap,
                                                   float* __restrict__ out,
                                                   u32* __restrict__ prog) {
  int b = blockIdx.x, role = blockIdx.y;
  int tid = threadIdx.x, lane = tid & 63, wid = tid >> 6;
  extern __shared__ char smem[];
  u16* s_Mbf = (u16*)smem;                 // consumer: 65536 u16; per-wave slices reused for f32 partials
  u16* s_rw = s_Mbf + 65536;               // consumer: 8192 u16 (swizzled 16B blocks)
  float* s_red = (float*)(s_rw + 8192);    // consumer: 2*128  |  producer: [2][16]

  const float* rb1 = rec1 + ((long)b << 17);
  const float* rb2 = rec2 + ((long)b << 18);
  float* wwb = ww_out + (long)b * 512 * 1024;
  u16* snb = snap + (long)b * 2097152;
  float* outb = out + (long)b * 512 * 512;

  if (role == 0) {
    // ================= producer: sequential write-path scan =================
    f32x2 m[32];
    {
      const float* M0r = M0 + (long)tid * 64;
      #pragma unroll
      for (int i = 0; i < 32; i++) m[i] = *(const f32x2*)(M0r + i * 2);
    }
    for (int t8 = 0; t8 < 64; ++t8) {
      if ((t8 & 1) == 0) {
        u16* sr = snb + ((long)(t8 >> 1) * 1024 + tid) * 64;
        #pragma unroll
        for (int i = 0; i < 8; i++) {
          u16x8 o;
          #pragma unroll
          for (int j = 0; j < 8; j++) { int e = i * 8 + j; o[j] = f2bf(m[e >> 1][e & 1]); }
          *(u16x8*)(sr + i * 8) = o;
        }
      }
      float wwreg[8];
      #pragma unroll
      for (int j = 0; j < 8; ++j) {
        int t = t8 * 8 + j;
        const float* kr = rb1 + ((long)t << 8);
        f32x2 n0 = {1e-8f, 0.f}, n1 = {0.f, 0.f};
        f32x2 d0 = {0.f, 0.f}, d1 = {0.f, 0.f};
        #pragma unroll
        for (int i = 0; i < 32; i += 2) {
          f32x2 k0 = *(const f32x2*)(kr + i * 2);
          f32x2 k1 = *(const f32x2*)(kr + i * 2 + 2);
          n0 = pk_fma_vvv(m[i], m[i], n0);
          d0 = pk_fma_svv(k0, m[i], d0);
          n1 = pk_fma_vvv(m[i + 1], m[i + 1], n1);
          d1 = pk_fma_svv(k1, m[i + 1], d1);
        }
        float n2 = (n0.x + n0.y) + (n1.x + n1.y);
        float dot = (d0.x + d0.y) + (d1.x + d1.y);
        float ew = __builtin_amdgcn_exp2f(dot * rsqrtf(n2));
        float ws = wred_sum_dpp(ew);
        if (!lane) s_red[(j & 1) * 16 + wid] = ws;
        __syncthreads();
        float tot;
        {
          const f32x4* rr = (const f32x4*)&s_red[(j & 1) * 16];
          f32x4 a = rr[0], bq = rr[1], cq = rr[2], dq = rr[3];
          tot = ((a.x + a.y) + (a.z + a.w)) + ((bq.x + bq.y) + (bq.z + bq.w)) +
                ((cq.x + cq.y) + (cq.z + cq.w)) + ((dq.x + dq.y) + (dq.z + dq.w));
        }
        float ww = kr[192] * ew * __builtin_amdgcn_rcpf(tot);
        wwreg[j] = ww;
        f32x2 ww2 = {ww, ww};
        #pragma unroll
        for (int i = 0; i < 32; i++) {
          f32x2 ne = *(const f32x2*)(kr + 64 + i * 2);
          f32x2 vv = *(const f32x2*)(kr + 128 + i * 2);
          f32x2 tt = pk_fma_svv(ne, m[i], vv);
          m[i] = pk_fma_vvv(ww2, tt, m[i]);
        }
      }
      #pragma unroll
      for (int j = 0; j < 8; ++j)
        wwb[(long)(t8 * 8 + j) * 1024 + tid] = wwreg[j];
      if (t8 & 1) {
        __syncthreads();  // drains each thread's vmcnt -> ww/snap stores in L2
        if (tid == 0)
          __hip_atomic_store(prog + b, (u32)((t8 + 1) >> 1),
                             __ATOMIC_RELEASE, __HIP_MEMORY_SCOPE_AGENT);
      }
    }
    __syncthreads();  // LDS handoff to consumer phase
  } else {
    if (tid == 0) {
      while (__hip_atomic_load(prog + b, __ATOMIC_ACQUIRE, __HIP_MEMORY_SCOPE_AGENT)
             < (u32)(role + 1))
        __builtin_amdgcn_s_sleep(16);
    }
    __syncthreads();
  }

  // ================= consumer: read-path replay for chunk c =================
  int c = role;
  f32x2 m[32];
  {
    const u16* sr = snap + (((long)b * 32 + c) * 1024 + tid) * 64;
    #pragma unroll
    for (int i = 0; i < 8; i++) {
      u16x8 v = *(const u16x8*)(sr + i * 8);
      #pragma unroll
      for (int j = 0; j < 8; j++) { int e = i * 8 + j; m[e >> 1][e & 1] = bf2f(v[j]); }
    }
  }
  int t0 = c * 16;
  int n7 = tid & 7;
  int blkswz = tid ^ ((tid >> 3) & 7);

  for (int ti = 0; ti < 16; ++ti) {
    int t = t0 + ti, cb = ti & 1;
    const float* kr1 = rb1 + ((long)t << 8);
    const float* kr2 = rb2 + ((long)t << 9);
    float ww = wwb[(long)t * 1024 + tid];
    __syncthreads();  // A: prior combine reads of Mbf slices done

    f32x2 ww2 = {ww, ww};
    f32x2 nn0 = {1e-8f, 0.f}, nn1 = {0.f, 0.f};
    #pragma unroll
    for (int i = 0; i < 32; i++) {
      f32x2 ne = *(const f32x2*)(kr1 + 64 + i * 2);
      f32x2 vv = *(const f32x2*)(kr1 + 128 + i * 2);
      f32x2 tt = pk_fma_svv(ne, m[i], vv);
      f32x2 mv = pk_fma_vvv(ww2, tt, m[i]);
      m[i] = mv;
      if (i & 1) nn1 = pk_fma_vvv(mv, mv, nn1);
      else       nn0 = pk_fma_vvv(mv, mv, nn0);
    }
    float invm = rsqrtf((nn0.x + nn0.y) + (nn1.x + nn1.y));
    #pragma unroll
    for (int i = 0; i < 8; i++) {
      u16x8 o;
      #pragma unroll
      for (int j = 0; j < 8; j++) { int e = i * 8 + j; o[j] = f2bf(m[e >> 1][e & 1]); }
      *(u16x8*)(s_Mbf + tid * 64 + ((i ^ n7) << 3)) = o;
    }
    float eh[8];
    u16x8 ehb;
    #pragma unroll
    for (int h = 0; h < 8; h++) {
      f32x2 a0 = {0.f, 0.f}, a1 = {0.f, 0.f};
      #pragma unroll
      for (int i = 0; i < 32; i += 2) {
        f32x2 k0 = *(const f32x2*)(kr2 + h * 64 + i * 2);
        f32x2 k1 = *(const f32x2*)(kr2 + h * 64 + i * 2 + 2);
        a0 = pk_fma_svv(k0, m[i], a0);
        a1 = pk_fma_svv(k1, m[i + 1], a1);
      }
      float d = (a0.x + a0.y) + (a1.x + a1.y);
      eh[h] = __builtin_amdgcn_exp2f(d * invm);
      ehb[h] = f2bf(eh[h]);
    }
    *(u16x8*)(s_rw + (blkswz << 3)) = ehb;
    #pragma unroll
    for (int h = 0; h < 8; h++) {
      float sh = wred_sum_dpp(eh[h]);
      if (!lane) s_red[cb * 128 + wid * 8 + h] = sh;
    }
    __syncthreads();  // B: s_rw + s_red + Mbf visible

    float p[8];
    #pragma unroll
    for (int h = 0; h < 8; h++) p[h] = 0.f;
    int rbase = wid << 6;
    int cblk = lane >> 3, cin = lane & 7;
    #pragma unroll 4
    for (int j = 0; j < 64; j++) {
      int r = rbase + j;
      float mf = bf2f(s_Mbf[(r << 6) + (((cblk ^ r) & 7) << 3) + cin]);
      int rsw = r ^ ((r >> 3) & 7);
      u32x4 rr = *(const u32x4*)(s_rw + (rsw << 3));
      p[0] = __builtin_fmaf(mf, blo(rr.x), p[0]); p[1] = __builtin_fmaf(mf, bhi(rr.x), p[1]);
      p[2] = __builtin_fmaf(mf, blo(rr.y), p[2]); p[3] = __builtin_fmaf(mf, bhi(rr.y), p[3]);
      p[4] = __builtin_fmaf(mf, blo(rr.z), p[4]); p[5] = __builtin_fmaf(mf, bhi(rr.z), p[5]);
      p[6] = __builtin_fmaf(mf, blo(rr.w), p[6]); p[7] = __builtin_fmaf(mf, bhi(rr.w), p[7]);
    }
    {
      float* pbw = (float*)(s_Mbf + (wid << 12));
      #pragma unroll
      for (int h = 0; h < 8; h++) pbw[h * 64 + lane] = p[h];
    }
    __syncthreads();  // C: partials ready

    if (tid < 512) {
      int h = tid >> 6, ow = tid & 63;
      float s = 0.f;
      #pragma unroll
      for (int j = 0; j < 16; j++) s += ((const float*)(s_Mbf + (j << 12)))[h * 64 + ow];
      float tt = 0.f;
      #pragma unroll
      for (int j = 0; j < 16; j++) tt += s_red[cb * 128 + j * 8 + h];
      outb[(long)t * 512 + tid] = s * __builtin_amdgcn_rcpf(tt);
    }
  }
}

// ---------------- host ----------------
static void launch_gemm(hipStream_t stream, const u16* A, int lda, const u16* B, int ldb,
                        const float* bias, float* oF, u16* oB, int ldc,
                        int M, int N, int K, int gz,
                        long sAb, long sAh, long sAz, long sBb, long sBh, long sBz,
                        long sCb, long sCh, long sCz, int zdiv, int z0, float alpha, int relu) {
  GemmP p;
  p.A = A; p.B = B; p.bias = bias; p.outF = oF; p.outB = oB;
  p.M = M; p.N = N; p.K = K; p.lda = lda; p.ldb = ldb; p.ldc = ldc;
  p.sAb = sAb; p.sAh = sAh; p.sAz = sAz;
  p.sBb = sBb; p.sBh = sBh; p.sBz = sBz;
  p.sCb = sCb; p.sCh = sCh; p.sCz = sCz;
  p.zdiv = zdiv; p.z0 = z0; p.alpha = alpha; p.relu = relu;
  dim3 g(M / 128, (N + 127) / 128, gz);
  gemm_k<<<g, 256, 0, stream>>>(p);
}

extern "C" void kernel_launch(void* const* d_in, const int* in_sizes, int n_in,
                              void* d_out, int out_size, void* d_ws, size_t ws_size,
                              hipStream_t stream) {
  (void)in_sizes; (void)n_in; (void)out_size; (void)ws_size;
  const float* x    = (const float*)d_in[0];
  const float* Wp   = (const float*)d_in[1];
  const float* bp   = (const float*)d_in[2];
  const float* Wqkv = (const float*)d_in[3];
  const float* bqkv = (const float*)d_in[4];
  const float* Wo   = (const float*)d_in[5];
  const float* bo   = (const float*)d_in[6];
  const float* ln1g = (const float*)d_in[7];
  const float* ln1b = (const float*)d_in[8];
  const float* W1   = (const float*)d_in[9];
  const float* b1   = (const float*)d_in[10];
  const float* W2   = (const float*)d_in[11];
  const float* b2   = (const float*)d_in[12];
  const float* ln2g = (const float*)d_in[13];
  const float* ln2b = (const float*)d_in[14];
  const float* Wi   = (const float*)d_in[15];
  const float* bi   = (const float*)d_in[16];
  const float* M0   = (const float*)d_in[17];
  float* outF = (float*)d_out;

  char* ws = (char*)d_ws;
  u16* WpT   = (u16*)ws;
  u16* WqkvT = WpT + 262144;
  u16* WoT   = WqkvT + 1572864;
  u16* W1T   = WoT + 524288;
  u16* W2T   = W1T + 2097152;
  u16* WiT   = W2T + 2097152;
  u16* xb    = WiT + 365568;
  u16* hb    = xb + 2097152;
  float* h   = (float*)(hb + 2097152);
  u16* qkvb  = (u16*)(h + 2097152);
  u16* vT    = qkvb + 6291456;
  float* scores = (float*)(vT + 2097152);
  u16* pbuf  = (u16*)(scores + 4194304);
  u16* obuf  = pbuf + 4194304;
  float* gout = (float*)(obuf + 2097152);
  u16* ffb   = (u16*)(gout + 2924544);
  float* ifbuf = (float*)(ffb + 8388608);
  // attention score/P overlay (bf16, 64*512*512 = 33.55MB) over gout+ffb+head of ifbuf
  u16* scoresB = (u16*)gout;
  // scan scratch (regions dead after the transformer):
  float* prepb1 = (float*)qkvb;        // 8*512*256 f32 = 4 MB
  float* prepb2 = prepb1 + 1048576;    // 8*512*512 f32 = 8 MB (both <= qkvb 12.58 MB)
  float* wwbuf = scores;               // 16 MB
  u16* snapb  = pbuf;                  // 32 MB (spans pbuf/obuf/gout/ffb-head, dead post-encoder)
  u32* progb  = (u32*)vT;              // 8 u32 (vT dead post-encoder)

  // casts / transposes
  castx_k<<<2048, 256, 0, stream>>>(x, xb, 524288);
  castT_k<<<dim3(1024, 1, 1), 256, 0, stream>>>(Wp, WpT, 512, 512);
  castT_k<<<dim3(3072, 1, 2), 256, 0, stream>>>(Wqkv, WqkvT, 512, 1536);
  castT_k<<<dim3(1024, 1, 2), 256, 0, stream>>>(Wo, WoT, 512, 512);
  castT_k<<<dim3(4096, 1, 2), 256, 0, stream>>>(W1, W1T, 512, 2048);
  castT_k<<<dim3(4096, 1, 2), 256, 0, stream>>>(W2, W2T, 2048, 512);
  castT_k<<<dim3(1428, 1, 1), 256, 0, stream>>>(Wi, WiT, 512, 714);

  // projection: h = x @ Wp + bp
  launch_gemm(stream, xb, 512, WpT, 512, bp, h, hb, 512, 4096, 512, 512,
              1, 0,0,0, 0,0,0, 0,0,0, 1, 0, 1.f, 0);

  for (int l = 0; l < 2; ++l) {
    launch_gemm(stream, hb, 512, WqkvT + (long)l * 786432, 512, bqkv + l * 1536,
                nullptr, qkvb, 1536, 4096, 1536, 512,
                1, 0,0,0, 0,0,0, 0,0,0, 1, 0, 1.f, 0);
    vtx_k<<<8192, 256, 0, stream>>>(qkvb, vT);
    // scores (bf16) for all 64 (b,h) in one launch
    launch_gemm(stream, qkvb, 1536, qkvb + 512, 1536, nullptr, nullptr, scoresB, 512,
                512, 512, 64, 64,
                786432, 64, 0,  786432, 64, 0,  2097152, 262144, 0, 8, 0, 0.125f, 0);
    smaxb_k<<<32768, 64, 0, stream>>>(scoresB);
    // o = P @ V for all 64 (b,h)
    launch_gemm(stream, scoresB, 512, vT, 512, nullptr, nullptr, obuf, 512,
                512, 64, 512, 64,
                2097152, 262144, 0,  262144, 32768, 0,  262144, 64, 0, 8, 0, 1.f, 0);
    launch_gemm(stream, obuf, 512, WoT + (long)l * 262144, 512, bo + l * 512,
                gout, nullptr, 512, 4096, 512, 512,
                1, 0,0,0, 0,0,0, 0,0,0, 1, 0, 1.f, 0);
    ln_k<<<4096, 64, 0, stream>>>(gout, h, ln1g + l * 512, ln1b + l * 512, h, hb);
    launch_gemm(stream, hb, 512, W1T + (long)l * 1048576, 512, b1 + l * 2048,
                nullptr, ffb, 2048, 4096, 2048, 512,
                1, 0,0,0, 0,0,0, 0,0,0, 1, 0, 1.f, 1);
    launch_gemm(stream, ffb, 2048, W2T + (long)l * 1048576, 2048, b2 + l * 512,
                gout, nullptr, 512, 4096, 512, 2048,
                1, 0,0,0, 0,0,0, 0,0,0, 1, 0, 1.f, 0);
    float* lnout = (l == 1) ? outF : h;
    ln_k<<<4096, 64, 0, stream>>>(gout, h, ln2g + l * 512, ln2b + l * 512, lnout, hb);
  }

  // iface = tout @ Wi + bi
  launch_gemm(stream, hb, 512, WiT, 512, bi, ifbuf, nullptr, 714,
              4096, 714, 512, 1, 0,0,0, 0,0,0, 0,0,0, 1, 0, 1.f, 0);

  // DNC: prep, then fused producer/consumer scan (write pass overlapped with replay)
  prep_k<<<1024, 256, 0, stream>>>(ifbuf, prepb1, prepb2);
  hipMemsetAsync(progb, 0, 8 * sizeof(u32), stream);
  hipFuncSetAttribute(reinterpret_cast<const void*>(fused_k),
                      hipFuncAttributeMaxDynamicSharedMemorySize, P2_LDS);
  fused_k<<<dim3(8, 32), 1024, P2_LDS, stream>>>(prepb1, prepb2, M0, wwbuf, snapb,
                                                 outF + 2097152, progb);
}

// Round 13
// 2276.148 us; speedup vs baseline: 2.6945x; 2.6945x over previous
//
#include <hip/hip_runtime.h>

typedef unsigned short u16;
typedef unsigned int u32;
typedef __attribute__((ext_vector_type(8))) short s16x8;
typedef __attribute__((ext_vector_type(8))) u16 u16x8;
typedef __attribute__((ext_vector_type(4))) u16 u16x4;
typedef __attribute__((ext_vector_type(4))) u32 u32x4;
typedef __attribute__((ext_vector_type(4))) float f32x4;
typedef __attribute__((ext_vector_type(2))) float f32x2;

#define L2E 1.4426950408889634f

__device__ __forceinline__ u16 f2bf(float f) {
  unsigned u = __builtin_bit_cast(unsigned, f);
  u = (u + 0x7fffu + ((u >> 16) & 1u)) >> 16;
  return (u16)u;
}
__device__ __forceinline__ float bf2f(u16 s) {
  unsigned u = ((unsigned)s) << 16;
  return __builtin_bit_cast(float, u);
}
__device__ __forceinline__ float blo(u32 d) { return __builtin_bit_cast(float, d << 16); }
__device__ __forceinline__ float bhi(u32 d) { return __builtin_bit_cast(float, d & 0xFFFF0000u); }
__device__ __forceinline__ float sigmoidf_(float x) { return 1.f / (1.f + __expf(-x)); }
__device__ __forceinline__ float softplusf_(float x) { return (x > 20.f) ? x : logf(1.f + __expf(x)); }

// packed f32 (VOP3P) helpers; _s* variants take the block-uniform operand in an SGPR pair
__device__ __forceinline__ f32x2 pk_fma_vvv(f32x2 a, f32x2 b, f32x2 c) {
  f32x2 d;
  asm("v_pk_fma_f32 %0, %1, %2, %3" : "=v"(d) : "v"(a), "v"(b), "v"(c));
  return d;
}
__device__ __forceinline__ f32x2 pk_fma_svv(f32x2 a, f32x2 b, f32x2 c) {
  f32x2 d;
  asm("v_pk_fma_f32 %0, %1, %2, %3" : "=v"(d) : "s"(a), "v"(b), "v"(c));
  return d;
}

__device__ __forceinline__ float wred_sum(float v) {
  #pragma unroll
  for (int d = 1; d < 64; d <<= 1) v += __shfl_xor(v, d);
  return v;
}
__device__ __forceinline__ float wred_max(float v) {
  #pragma unroll
  for (int d = 1; d < 64; d <<= 1) v = fmaxf(v, __shfl_xor(v, d));
  return v;
}

// ---------------- cast kernels ----------------
__global__ void castx_k(const float* __restrict__ in, u16* __restrict__ out, int n4) {
  int i = blockIdx.x * 256 + threadIdx.x;
  if (i < n4) {
    f32x4 v = *(const f32x4*)(in + (long)i * 4);
    u16x4 o;
    o.x = f2bf(v.x); o.y = f2bf(v.y); o.z = f2bf(v.z); o.w = f2bf(v.w);
    *(u16x4*)(out + (long)i * 4) = o;
  }
}

// f32 (K,N) row-major -> bf16 (N,K) row-major, batched over z
__global__ void castT_k(const float* __restrict__ in, u16* __restrict__ out, int K, int N) {
  long base = (long)blockIdx.z * K * N;
  int idx = blockIdx.x * 256 + threadIdx.x;
  if (idx < K * N) {
    int n = idx / K, k = idx - n * K;
    out[base + idx] = f2bf(in[base + (long)k * N + n]);
  }
}

// extract transposed V: vT[(b,h)][d][s] = qkv[(b,s)][2H + h*64 + d]
__global__ void vtx_k(const u16* __restrict__ qkv, u16* __restrict__ vT) {
  int idx = blockIdx.x * 256 + threadIdx.x;
  int s = idx & 511;
  int d = (idx >> 9) & 63;
  int bh = idx >> 15;
  int b = bh >> 3, h = bh & 7;
  vT[idx] = qkv[((long)(b * 512 + s)) * 1536 + 1024 + h * 64 + d];
}

// ---------------- GEMM (bf16 MFMA, B passed as B^T = (N,K) row-major) ----------------
struct GemmP {
  const u16* A; const u16* B; const float* bias;
  float* outF; u16* outB;
  int M, N, K, lda, ldb, ldc;
  long sAb, sAh, sAz, sBb, sBh, sBz, sCb, sCh, sCz;
  int zdiv, z0;
  float alpha; int relu;
};

__global__ __launch_bounds__(256) void gemm_k(GemmP p) {
  __shared__ u16 sA[128 * 72];
  __shared__ u16 sB[128 * 72];
  int tid = threadIdx.x;
  int gp = p.z0 + blockIdx.z;
  int zb = gp / p.zdiv, zh = gp - zb * p.zdiv;
  const u16* Ab = p.A + zb * p.sAb + zh * p.sAh + (long)blockIdx.z * p.sAz + (long)blockIdx.x * 128 * p.lda;
  const u16* Bb = p.B + zb * p.sBb + zh * p.sBh + (long)blockIdx.z * p.sBz;
  long coff = zb * p.sCb + zh * p.sCh + (long)blockIdx.z * p.sCz;
  int bn = blockIdx.y * 128;
  int lane = tid & 63, wid = tid >> 6;
  int wr = wid >> 1, wc = wid & 1;

  f32x4 acc[4][4];
  f32x4 z4 = {0.f, 0.f, 0.f, 0.f};
  #pragma unroll
  for (int i = 0; i < 4; i++)
    #pragma unroll
    for (int j = 0; j < 4; j++) acc[i][j] = z4;

  int r = tid >> 1, c32 = (tid & 1) * 32;
  for (int k0 = 0; k0 < p.K; k0 += 64) {
    const u16* Ag = Ab + (long)r * p.lda + k0 + c32;
    u16x8* dA = (u16x8*)(sA + r * 72 + c32);
    #pragma unroll
    for (int i = 0; i < 4; i++) dA[i] = *(const u16x8*)(Ag + i * 8);
    int nrow = bn + r;
    u16x8* dB = (u16x8*)(sB + r * 72 + c32);
    if (nrow < p.N) {
      const u16* Bg = Bb + (long)nrow * p.ldb + k0 + c32;
      #pragma unroll
      for (int i = 0; i < 4; i++) dB[i] = *(const u16x8*)(Bg + i * 8);
    } else {
      u16x8 zz = (u16x8)0;
      #pragma unroll
      for (int i = 0; i < 4; i++) dB[i] = zz;
    }
    __syncthreads();
    #pragma unroll
    for (int ks = 0; ks < 2; ks++) {
      int ko = ks * 32 + (lane >> 4) * 8;
      s16x8 af[4], bf[4];
      #pragma unroll
      for (int m = 0; m < 4; m++) af[m] = *(const s16x8*)(sA + (wr * 64 + m * 16 + (lane & 15)) * 72 + ko);
      #pragma unroll
      for (int n = 0; n < 4; n++) bf[n] = *(const s16x8*)(sB + (wc * 64 + n * 16 + (lane & 15)) * 72 + ko);
      #pragma unroll
      for (int m = 0; m < 4; m++)
        #pragma unroll
        for (int n = 0; n < 4; n++)
          acc[m][n] = __builtin_amdgcn_mfma_f32_16x16x32_bf16(af[m], bf[n], acc[m][n], 0, 0, 0);
    }
    __syncthreads();
  }

  int row0 = blockIdx.x * 128 + wr * 64;
  int col0 = bn + wc * 64;
  #pragma unroll
  for (int n = 0; n < 4; n++) {
    int col = col0 + n * 16 + (lane & 15);
    if (col >= p.N) continue;
    float bv = p.bias ? p.bias[col] : 0.f;
    #pragma unroll
    for (int m = 0; m < 4; m++) {
      #pragma unroll
      for (int q = 0; q < 4; q++) {
        int row = row0 + m * 16 + (lane >> 4) * 4 + q;
        float v = acc[m][n][q] * p.alpha + bv;
        if (p.relu) v = fmaxf(v, 0.f);
        long ci = coff + (long)row * p.ldc + col;
        if (p.outF) p.outF[ci] = v;
        if (p.outB) p.outB[ci] = f2bf(v);
      }
    }
  }
}

// ---------------- fused residual + LayerNorm ----------------
__global__ __launch_bounds__(64) void ln_k(const float* __restrict__ a, const float* __restrict__ res,
                                           const float* __restrict__ g, const float* __restrict__ bb,
                                           float* __restrict__ outF, u16* __restrict__ outB) {
  int row = blockIdx.x, t = threadIdx.x;
  const float* ar = a + (long)row * 512;
  const float* rr = res + (long)row * 512;
  float x[8];
  float s1 = 0.f;
  #pragma unroll
  for (int i = 0; i < 8; i++) { x[i] = ar[i * 64 + t] + rr[i * 64 + t]; s1 += x[i]; }
  s1 = wred_sum(s1);
  float mean = s1 * (1.f / 512.f);
  float s2 = 0.f;
  #pragma unroll
  for (int i = 0; i < 8; i++) { float d = x[i] - mean; s2 += d * d; }
  s2 = wred_sum(s2);
  float inv = rsqrtf(s2 * (1.f / 512.f) + 1e-5f);
  #pragma unroll
  for (int i = 0; i < 8; i++) {
    int cc = i * 64 + t;
    float y = (x[i] - mean) * inv * g[cc] + bb[cc];
    outF[(long)row * 512 + cc] = y;
    outB[(long)row * 512 + cc] = f2bf(y);
  }
}

// ---------------- row softmax over bf16 (512 cols), in place ----------------
__global__ __launch_bounds__(64) void smaxb_k(u16* __restrict__ p) {
  long row = blockIdx.x;
  u16* pr = p + row * 512;
  int t = threadIdx.x;
  u16x8 v = *(const u16x8*)(pr + t * 8);
  float f[8];
  float mx = -1e30f;
  #pragma unroll
  for (int i = 0; i < 8; i++) { f[i] = bf2f(v[i]); mx = fmaxf(mx, f[i]); }
  mx = wred_max(mx);
  float se = 0.f;
  #pragma unroll
  for (int i = 0; i < 8; i++) { f[i] = __expf(f[i] - mx); se += f[i]; }
  se = wred_sum(se);
  float inv = __builtin_amdgcn_rcpf(se);
  #pragma unroll
  for (int i = 0; i < 8; i++) v[i] = f2bf(f[i] * inv);
  *(u16x8*)(pr + t * 8) = v;
}

// ---------------- DNC prep: fold norms/betas/log2e into keys, apply gates ----------------
// rec1 (stride 256 f32): [0:64]=wk*(wb*log2e/|wk|), [64:128]=-sigmoid(er),
//                        [128:192]=wv, [192]=gw
// rec2 (stride 512 f32): rk_h*(rb_h*log2e/|rk_h|)
__global__ __launch_bounds__(256) void prep_k(const float* __restrict__ iface,
                                              float* __restrict__ rec1,
                                              float* __restrict__ rec2) {
  int idx = blockIdx.x * 4 + (threadIdx.x >> 6);
  int lane = threadIdx.x & 63;
  const float* r = iface + (long)idx * 714;
  float* o1 = rec1 + ((long)idx << 8);
  float* o2 = rec2 + ((long)idx << 9);
  float wk = r[520 + lane];
  float s2k = wred_sum(wk * wk);
  float wb = softplusf_(r[584]);
  o1[lane] = wk * (wb * L2E * rsqrtf(s2k + 1e-8f));
  o1[64 + lane] = -sigmoidf_(r[585 + lane]);
  o1[128 + lane] = r[649 + lane];
  #pragma unroll
  for (int h = 0; h < 8; h++) {
    float rk = r[h * 64 + lane];
    float s2r = wred_sum(rk * rk);
    float rb = softplusf_(r[512 + h]);
    o2[h * 64 + lane] = rk * (rb * L2E * rsqrtf(s2r + 1e-8f));
  }
  if (!lane) o1[192] = sigmoidf_(r[713]);
}

// ---------------- DNC pass 1: sequential write-path scan ----------------
// 8 blocks (one per batch), 1024 threads, thread owns M row tid as f32x2 m[32].
// k/ne/v/gw block-uniform -> scalar loads (rec1 only, 832B/step); packed-f32 VALU.
__global__ __launch_bounds__(1024, 4) void scan1_k(const float* __restrict__ rec1,
                                                   const float* __restrict__ M0,
                                                   float* __restrict__ ww_out,
                                                   u16* __restrict__ snap) {
  int b = blockIdx.x, tid = threadIdx.x, lane = tid & 63, wid = tid >> 6;
  __shared__ float s_red[2][16];
  f32x2 m[32];
  {
    const float* M0r = M0 + (long)tid * 64;
    #pragma unroll
    for (int i = 0; i < 32; i++) m[i] = *(const f32x2*)(M0r + i * 2);
  }
  const float* rb_ = rec1 + ((long)b << 17);  // b*512*256
  float* wwb = ww_out + (long)b * 512 * 1024;
  u16* snb = snap + (long)b * 2097152;

  for (int t = 0; t < 512; ++t) {
    const float* kr = rb_ + ((long)t << 8);
    if ((t & 15) == 0) {
      u16* sr = snb + ((long)(t >> 4) * 1024 + tid) * 64;
      #pragma unroll
      for (int i = 0; i < 8; i++) {
        u16x8 o;
        #pragma unroll
        for (int j = 0; j < 8; j++) { int e = i * 8 + j; o[j] = f2bf(m[e >> 1][e & 1]); }
        *(u16x8*)(sr + i * 8) = o;
      }
    }
    // norm + write-dot (k' uniform, packed)
    f32x2 n0 = {1e-8f, 0.f}, n1 = {0.f, 0.f};
    f32x2 d0 = {0.f, 0.f}, d1 = {0.f, 0.f};
    #pragma unroll
    for (int i = 0; i < 32; i += 2) {
      f32x2 k0 = *(const f32x2*)(kr + i * 2);
      f32x2 k1 = *(const f32x2*)(kr + i * 2 + 2);
      n0 = pk_fma_vvv(m[i], m[i], n0);
      d0 = pk_fma_svv(k0, m[i], d0);
      n1 = pk_fma_vvv(m[i + 1], m[i + 1], n1);
      d1 = pk_fma_svv(k1, m[i + 1], d1);
    }
    float n2 = (n0.x + n0.y) + (n1.x + n1.y);
    float dot = (d0.x + d0.y) + (d1.x + d1.y);
    float ew = __builtin_amdgcn_exp2f(dot * rsqrtf(n2));
    float ssum = wred_sum(ew);
    if (!lane) s_red[t & 1][wid] = ssum;
    __syncthreads();
    float tot;
    {
      const f32x4* rr = (const f32x4*)&s_red[t & 1][0];
      f32x4 a = rr[0], bq = rr[1], cq = rr[2], dq = rr[3];
      tot = ((a.x + a.y) + (a.z + a.w)) + ((bq.x + bq.y) + (bq.z + bq.w)) +
            ((cq.x + cq.y) + (cq.z + cq.w)) + ((dq.x + dq.y) + (dq.z + dq.w));
    }
    float ww = kr[192] * ew * __builtin_amdgcn_rcpf(tot);
    wwb[(long)t * 1024 + tid] = ww;

    // m += ww * (v - e*m)  via negated-e: t = fma(ne, m, v); m = fma(ww, t, m)
    f32x2 ww2 = {ww, ww};
    #pragma unroll
    for (int i = 0; i < 32; i++) {
      f32x2 ne = *(const f32x2*)(kr + 64 + i * 2);
      f32x2 vv = *(const f32x2*)(kr + 128 + i * 2);
      f32x2 tt = pk_fma_svv(ne, m[i], vv);
      m[i] = pk_fma_vvv(ww2, tt, m[i]);
    }
  }
}

// ---------------- DNC pass 2: parallel read-path replay ----------------
// grid (8 batches, 32 chunks of 16 steps), 1024 threads, 1 row/thread.
// ne/v from rec1, rk' from rec2 (scalar loads); packed-f32; LDS for phase-D reduce.
#define P2_LDS 148480
__global__ __launch_bounds__(1024, 4) void scan2_k(const float* __restrict__ rec1,
                                                   const float* __restrict__ rec2,
                                                   const float* __restrict__ ww_in,
                                                   const u16* __restrict__ snap,
                                                   float* __restrict__ out) {
  int b = blockIdx.x, c = blockIdx.y, tid = threadIdx.x, lane = tid & 63, wid = tid >> 6;
  extern __shared__ char smem[];
  u16* s_Mbf = (u16*)smem;                 // 65536 u16 (128KB); per-wave 4K-u16 slices reused for f32 partials
  u16* s_rw = s_Mbf + 65536;               // 8192 u16 (swizzled 16B blocks)
  float* s_red = (float*)(s_rw + 8192);    // 2*128

  f32x2 m[32];
  {
    const u16* sr = snap + (((long)b * 32 + c) * 1024 + tid) * 64;
    #pragma unroll
    for (int i = 0; i < 8; i++) {
      u16x8 v = *(const u16x8*)(sr + i * 8);
      #pragma unroll
      for (int j = 0; j < 8; j++) { int e = i * 8 + j; m[e >> 1][e & 1] = bf2f(v[j]); }
    }
  }
  const float* rb1 = rec1 + ((long)b << 17);
  const float* rb2 = rec2 + ((long)b << 18);
  const float* wwb = ww_in + (long)b * 512 * 1024;
  float* outb = out + (long)b * 512 * 512;
  int t0 = c * 16;
  int n7 = tid & 7;
  int blkswz = tid ^ ((tid >> 3) & 7);

  for (int ti = 0; ti < 16; ++ti) {
    int t = t0 + ti, cb = ti & 1;
    const float* kr1 = rb1 + ((long)t << 8);
    const float* kr2 = rb2 + ((long)t << 9);
    float ww = wwb[(long)t * 1024 + tid];
    __syncthreads();  // A: prior combine reads of Mbf slices done

    // replay M update (packed, 2-op), fused norm
    f32x2 ww2 = {ww, ww};
    f32x2 nn0 = {1e-8f, 0.f}, nn1 = {0.f, 0.f};
    #pragma unroll
    for (int i = 0; i < 32; i++) {
      f32x2 ne = *(const f32x2*)(kr1 + 64 + i * 2);
      f32x2 vv = *(const f32x2*)(kr1 + 128 + i * 2);
      f32x2 tt = pk_fma_svv(ne, m[i], vv);
      f32x2 mv = pk_fma_vvv(ww2, tt, m[i]);
      m[i] = mv;
      if (i & 1) nn1 = pk_fma_vvv(mv, mv, nn1);
      else       nn0 = pk_fma_vvv(mv, mv, nn0);
    }
    float invm = rsqrtf((nn0.x + nn0.y) + (nn1.x + nn1.y));
    // own row -> LDS bf16 (16B-block swizzle within the 128B row)
    #pragma unroll
    for (int i = 0; i < 8; i++) {
      u16x8 o;
      #pragma unroll
      for (int j = 0; j < 8; j++) { int e = i * 8 + j; o[j] = f2bf(m[e >> 1][e & 1]); }
      *(u16x8*)(s_Mbf + tid * 64 + ((i ^ n7) << 3)) = o;
    }
    // 8 read dots (rk' uniform, packed) + exp2
    float eh[8];
    u16x8 ehb;
    #pragma unroll
    for (int h = 0; h < 8; h++) {
      f32x2 a0 = {0.f, 0.f}, a1 = {0.f, 0.f};
      #pragma unroll
      for (int i = 0; i < 32; i += 2) {
        f32x2 k0 = *(const f32x2*)(kr2 + h * 64 + i * 2);
        f32x2 k1 = *(const f32x2*)(kr2 + h * 64 + i * 2 + 2);
        a0 = pk_fma_svv(k0, m[i], a0);
        a1 = pk_fma_svv(k1, m[i + 1], a1);
      }
      float d = (a0.x + a0.y) + (a1.x + a1.y);
      eh[h] = __builtin_amdgcn_exp2f(d * invm);
      ehb[h] = f2bf(eh[h]);
    }
    *(u16x8*)(s_rw + (blkswz << 3)) = ehb;
    #pragma unroll
    for (int h = 0; h < 8; h++) {
      float sh = wred_sum(eh[h]);
      if (!lane) s_red[cb * 128 + wid * 8 + h] = sh;
    }
    __syncthreads();  // B: s_rw + s_red + Mbf visible

    // phase D: wave wid sums its 64 rows for all 8 heads; lane = word
    float p[8];
    #pragma unroll
    for (int h = 0; h < 8; h++) p[h] = 0.f;
    int rbase = wid << 6;
    int cblk = lane >> 3, cin = lane & 7;
    #pragma unroll 4
    for (int j = 0; j < 64; j++) {
      int r = rbase + j;
      float mf = bf2f(s_Mbf[(r << 6) + (((cblk ^ r) & 7) << 3) + cin]);
      int rsw = r ^ ((r >> 3) & 7);
      u32x4 rr = *(const u32x4*)(s_rw + (rsw << 3));
      p[0] = __builtin_fmaf(mf, blo(rr.x), p[0]); p[1] = __builtin_fmaf(mf, bhi(rr.x), p[1]);
      p[2] = __builtin_fmaf(mf, blo(rr.y), p[2]); p[3] = __builtin_fmaf(mf, bhi(rr.y), p[3]);
      p[4] = __builtin_fmaf(mf, blo(rr.z), p[4]); p[5] = __builtin_fmaf(mf, bhi(rr.z), p[5]);
      p[6] = __builtin_fmaf(mf, blo(rr.w), p[6]); p[7] = __builtin_fmaf(mf, bhi(rr.w), p[7]);
    }
    // f32 partials into this wave's own (already-consumed) Mbf slice
    {
      float* pbw = (float*)(s_Mbf + (wid << 12));
      #pragma unroll
      for (int h = 0; h < 8; h++) pbw[h * 64 + lane] = p[h];
    }
    __syncthreads();  // C: partials ready

    if (tid < 512) {
      int h = tid >> 6, ow = tid & 63;
      float s = 0.f;
      #pragma unroll
      for (int j = 0; j < 16; j++) s += ((const float*)(s_Mbf + (j << 12)))[h * 64 + ow];
      float tt = 0.f;
      #pragma unroll
      for (int j = 0; j < 16; j++) tt += s_red[cb * 128 + j * 8 + h];
      outb[(long)t * 512 + tid] = s * __builtin_amdgcn_rcpf(tt);
    }
  }
}

// ---------------- host ----------------
static void launch_gemm(hipStream_t stream, const u16* A, int lda, const u16* B, int ldb,
                        const float* bias, float* oF, u16* oB, int ldc,
                        int M, int N, int K, int gz,
                        long sAb, long sAh, long sAz, long sBb, long sBh, long sBz,
                        long sCb, long sCh, long sCz, int zdiv, int z0, float alpha, int relu) {
  GemmP p;
  p.A = A; p.B = B; p.bias = bias; p.outF = oF; p.outB = oB;
  p.M = M; p.N = N; p.K = K; p.lda = lda; p.ldb = ldb; p.ldc = ldc;
  p.sAb = sAb; p.sAh = sAh; p.sAz = sAz;
  p.sBb = sBb; p.sBh = sBh; p.sBz = sBz;
  p.sCb = sCb; p.sCh = sCh; p.sCz = sCz;
  p.zdiv = zdiv; p.z0 = z0; p.alpha = alpha; p.relu = relu;
  dim3 g(M / 128, (N + 127) / 128, gz);
  gemm_k<<<g, 256, 0, stream>>>(p);
}

extern "C" void kernel_launch(void* const* d_in, const int* in_sizes, int n_in,
                              void* d_out, int out_size, void* d_ws, size_t ws_size,
                              hipStream_t stream) {
  (void)in_sizes; (void)n_in; (void)out_size; (void)ws_size;
  const float* x    = (const float*)d_in[0];
  const float* Wp   = (const float*)d_in[1];
  const float* bp   = (const float*)d_in[2];
  const float* Wqkv = (const float*)d_in[3];
  const float* bqkv = (const float*)d_in[4];
  const float* Wo   = (const float*)d_in[5];
  const float* bo   = (const float*)d_in[6];
  const float* ln1g = (const float*)d_in[7];
  const float* ln1b = (const float*)d_in[8];
  const float* W1   = (const float*)d_in[9];
  const float* b1   = (const float*)d_in[10];
  const float* W2   = (const float*)d_in[11];
  const float* b2   = (const float*)d_in[12];
  const float* ln2g = (const float*)d_in[13];
  const float* ln2b = (const float*)d_in[14];
  const float* Wi   = (const float*)d_in[15];
  const float* bi   = (const float*)d_in[16];
  const float* M0   = (const float*)d_in[17];
  float* outF = (float*)d_out;

  char* ws = (char*)d_ws;
  u16* WpT   = (u16*)ws;
  u16* WqkvT = WpT + 262144;
  u16* WoT   = WqkvT + 1572864;
  u16* W1T   = WoT + 524288;
  u16* W2T   = W1T + 2097152;
  u16* WiT   = W2T + 2097152;
  u16* xb    = WiT + 365568;
  u16* hb    = xb + 2097152;
  float* h   = (float*)(hb + 2097152);
  u16* qkvb  = (u16*)(h + 2097152);
  u16* vT    = qkvb + 6291456;
  float* scores = (float*)(vT + 2097152);
  u16* pbuf  = (u16*)(scores + 4194304);
  u16* obuf  = pbuf + 4194304;
  float* gout = (float*)(obuf + 2097152);
  u16* ffb   = (u16*)(gout + 2924544);
  float* ifbuf = (float*)(ffb + 8388608);
  // attention score/P overlay (bf16, 64*512*512 = 33.55MB) over gout+ffb+head of ifbuf
  u16* scoresB = (u16*)gout;
  // scan scratch (regions dead after the transformer):
  float* prepb1 = (float*)qkvb;        // 8*512*256 f32 = 4 MB
  float* prepb2 = prepb1 + 1048576;    // 8*512*512 f32 = 8 MB (both <= qkvb 12.58 MB)
  float* wwbuf = scores;               // 16 MB
  u16* snapb  = pbuf;                  // 32 MB (spans pbuf/obuf/gout/ffb-head, dead post-encoder)

  // casts / transposes
  castx_k<<<2048, 256, 0, stream>>>(x, xb, 524288);
  castT_k<<<dim3(1024, 1, 1), 256, 0, stream>>>(Wp, WpT, 512, 512);
  castT_k<<<dim3(3072, 1, 2), 256, 0, stream>>>(Wqkv, WqkvT, 512, 1536);
  castT_k<<<dim3(1024, 1, 2), 256, 0, stream>>>(Wo, WoT, 512, 512);
  castT_k<<<dim3(4096, 1, 2), 256, 0, stream>>>(W1, W1T, 512, 2048);
  castT_k<<<dim3(4096, 1, 2), 256, 0, stream>>>(W2, W2T, 2048, 512);
  castT_k<<<dim3(1428, 1, 1), 256, 0, stream>>>(Wi, WiT, 512, 714);

  // projection: h = x @ Wp + bp
  launch_gemm(stream, xb, 512, WpT, 512, bp, h, hb, 512, 4096, 512, 512,
              1, 0,0,0, 0,0,0, 0,0,0, 1, 0, 1.f, 0);

  for (int l = 0; l < 2; ++l) {
    launch_gemm(stream, hb, 512, WqkvT + (long)l * 786432, 512, bqkv + l * 1536,
                nullptr, qkvb, 1536, 4096, 1536, 512,
                1, 0,0,0, 0,0,0, 0,0,0, 1, 0, 1.f, 0);
    vtx_k<<<8192, 256, 0, stream>>>(qkvb, vT);
    // scores (bf16) for all 64 (b,h) in one launch
    launch_gemm(stream, qkvb, 1536, qkvb + 512, 1536, nullptr, nullptr, scoresB, 512,
                512, 512, 64, 64,
                786432, 64, 0,  786432, 64, 0,  2097152, 262144, 0, 8, 0, 0.125f, 0);
    smaxb_k<<<32768, 64, 0, stream>>>(scoresB);
    // o = P @ V for all 64 (b,h)
    launch_gemm(stream, scoresB, 512, vT, 512, nullptr, nullptr, obuf, 512,
                512, 64, 512, 64,
                2097152, 262144, 0,  262144, 32768, 0,  262144, 64, 0, 8, 0, 1.f, 0);
    launch_gemm(stream, obuf, 512, WoT + (long)l * 262144, 512, bo + l * 512,
                gout, nullptr, 512, 4096, 512, 512,
                1, 0,0,0, 0,0,0, 0,0,0, 1, 0, 1.f, 0);
    ln_k<<<4096, 64, 0, stream>>>(gout, h, ln1g + l * 512, ln1b + l * 512, h, hb);
    launch_gemm(stream, hb, 512, W1T + (long)l * 1048576, 512, b1 + l * 2048,
                nullptr, ffb, 2048, 4096, 2048, 512,
                1, 0,0,0, 0,0,0, 0,0,0, 1, 0, 1.f, 1);
    launch_gemm(stream, ffb, 2048, W2T + (long)l * 1048576, 2048, b2 + l * 512,
                gout, nullptr, 512, 4096, 512, 2048,
                1, 0,0,0, 0,0,0, 0,0,0, 1, 0, 1.f, 0);
    float* lnout = (l == 1) ? outF : h;
    ln_k<<<4096, 64, 0, stream>>>(gout, h, ln2g + l * 512, ln2b + l * 512, lnout, hb);
  }

  // iface = tout @ Wi + bi
  launch_gemm(stream, hb, 512, WiT, 512, bi, ifbuf, nullptr, 714,
              4096, 714, 512, 1, 0,0,0, 0,0,0, 0,0,0, 1, 0, 1.f, 0);

  // DNC: prep (fold norms/betas, split records), sequential write pass, parallel read replay
  prep_k<<<1024, 256, 0, stream>>>(ifbuf, prepb1, prepb2);
  scan1_k<<<8, 1024, 0, stream>>>(prepb1, M0, wwbuf, snapb);
  hipFuncSetAttribute(reinterpret_cast<const void*>(scan2_k),
                      hipFuncAttributeMaxDynamicSharedMemorySize, P2_LDS);
  scan2_k<<<dim3(8, 32), 1024, P2_LDS, stream>>>(prepb1, prepb2, wwbuf, snapb, outF + 2097152);
}